// Round 1
// baseline (356.228 us; speedup 1.0000x reference)
//
#include <hip/hip_runtime.h>
#include <hip/hip_bf16.h>

typedef __attribute__((ext_vector_type(8))) short bf16x8;
typedef __attribute__((ext_vector_type(4))) float f32x4;
typedef unsigned short u16;

__device__ __forceinline__ u16 f2b(float f) {
  __hip_bfloat16 h = __float2bfloat16(f);
  return __builtin_bit_cast(unsigned short, h);
}
__device__ __forceinline__ float b2f(u16 u) {
  __hip_bfloat16 h = __builtin_bit_cast(__hip_bfloat16, u);
  return __bfloat162float(h);
}

// Stage a [128 rows x 64 k (128B)] bf16 tile into LDS via global_load_lds(16B),
// with st-style XOR swizzle applied on the GLOBAL source address (LDS dest must
// stay linear: wave-uniform base + lane*16). Read side applies the same XOR.
__device__ __forceinline__ void stage_tile(char* sbase, const char* gbase, int ld_bytes, int tid) {
#pragma unroll
  for (int i = 0; i < 4; ++i) {
    int o = (i * 256 + tid) * 16;
    int row = o >> 7;
    int cb = o & 127;
    int scb = cb ^ ((row & 7) << 4);
    const char* src = gbase + (long)row * ld_bytes + scb;
    __builtin_amdgcn_global_load_lds((const __attribute__((address_space(1))) void*)src,
                                     (__attribute__((address_space(3))) void*)(sbase + o),
                                     16, 0, 0);
  }
}

#define EPI_HID 0
#define EPI_QK 1
#define EPI_ATTN 2
#define EPI_PV 3
#define EPI_OUT 4

// TN GEMM: C[M,N] = A[M,K] * BT[N,K]^T, 128x128 tile, BK=64, 4 waves (2x2),
// each wave 64x64 via 4x4 frags of mfma_f32_16x16x32_bf16.
template <int EPI>
__global__ __launch_bounds__(256, 2) void gemm_tn(
    const char* Ab, const char* Bb, long sAbat, long sBbat,
    int lda_b, int ldb_b, int nkt,
    u16* o0, u16* o1,
    const float* a0, const float* a1, const float* a2, const float* a3,
    float* fout, const float* xres) {
  __shared__ __align__(16) char lds[32768];
  char* sA = lds;
  char* sB = lds + 16384;
  const int tid = threadIdx.x;
  const int lane = tid & 63;
  const int wave = tid >> 6;
  const int wm = wave >> 1, wn = wave & 1;
  const int l16 = lane & 15, lq = lane >> 4;
  const int bat = blockIdx.z;
  const int row0 = blockIdx.y * 128;
  const int col0 = blockIdx.x * 128;

  const char* Abase = Ab + (long)bat * sAbat + (long)row0 * lda_b;
  const char* Bbase = Bb + (long)bat * sBbat + (long)col0 * ldb_b;

  f32x4 acc[4][4];
#pragma unroll
  for (int i = 0; i < 4; ++i)
#pragma unroll
    for (int j = 0; j < 4; ++j) acc[i][j] = (f32x4){0.f, 0.f, 0.f, 0.f};

  for (int kt = 0; kt < nkt; ++kt) {
    stage_tile(sA, Abase + (long)kt * 128, lda_b, tid);
    stage_tile(sB, Bbase + (long)kt * 128, ldb_b, tid);
    __syncthreads();
#pragma unroll
    for (int kk = 0; kk < 2; ++kk) {
      bf16x8 af[4], bfr[4];
#pragma unroll
      for (int mf = 0; mf < 4; ++mf) {
        int r = wm * 64 + mf * 16 + l16;
        int kb = kk * 64 + lq * 16;
        af[mf] = *(const bf16x8*)(sA + r * 128 + (kb ^ ((r & 7) << 4)));
      }
#pragma unroll
      for (int nf = 0; nf < 4; ++nf) {
        int r = wn * 64 + nf * 16 + l16;
        int kb = kk * 64 + lq * 16;
        bfr[nf] = *(const bf16x8*)(sB + r * 128 + (kb ^ ((r & 7) << 4)));
      }
#pragma unroll
      for (int mf = 0; mf < 4; ++mf)
#pragma unroll
        for (int nf = 0; nf < 4; ++nf)
          acc[mf][nf] = __builtin_amdgcn_mfma_f32_16x16x32_bf16(af[mf], bfr[nf], acc[mf][nf], 0, 0, 0);
    }
    __syncthreads();
  }

  // Epilogue. D frag: lane holds rows (lq*4 + i), col l16 (m89-verified layout).
#pragma unroll
  for (int mf = 0; mf < 4; ++mf) {
#pragma unroll
    for (int nf = 0; nf < 4; ++nf) {
      const int row = row0 + wm * 64 + mf * 16 + lq * 4;
      const int col = col0 + wn * 64 + nf * 16 + l16;
      f32x4 v = acc[mf][nf];
      if constexpr (EPI == EPI_HID) {
        // hid = x*Wh + b; cols<1024 -> v transposed [h][m], cols>=1024 -> gate transposed [h][m]
        float bias = a0[col];
        u16* dst = (col < 1024) ? (o0 + (size_t)col * 16384 + row)
                                : (o1 + (size_t)(col - 1024) * 16384 + row);
        ushort4 pk = make_ushort4(f2b(v.x + bias), f2b(v.y + bias), f2b(v.z + bias), f2b(v.w + bias));
        *(ushort4*)dst = pk;
      } else if constexpr (EPI == EPI_QK) {
        float qg = a0[col], qbt = a1[col], kg = a2[col], kbt = a3[col];
#pragma unroll
        for (int i = 0; i < 4; ++i) {
          float t = v[i];
          o0[(size_t)(row + i) * 128 + col] = f2b(t * qg + qbt);
          o1[(size_t)(row + i) * 128 + col] = f2b(t * kg + kbt);
        }
      } else if constexpr (EPI == EPI_ATTN) {
        const float scale = 0.088388347648318447f;  // 128^-0.5
        u16* dst = o0 + (size_t)bat * 4096 * 4096;
#pragma unroll
        for (int i = 0; i < 4; ++i) {
          float t = v[i] * scale;
          t = t > 0.f ? t * t : 0.f;
          dst[(size_t)(row + i) * 4096 + col] = f2b(t);
        }
      } else if constexpr (EPI == EPI_PV) {
        // out1 = (attn@v) * gate ; gate stored transposed [h][m] so 4 rows are contiguous
        const u16* gt = o1 + (size_t)col * 16384 + (size_t)bat * 4096 + row;
        ushort4 g = *(const ushort4*)gt;
        u16* dst = o0 + (size_t)bat * 4096 * 1024;
        dst[(size_t)(row + 0) * 1024 + col] = f2b(v.x * b2f(g.x));
        dst[(size_t)(row + 1) * 1024 + col] = f2b(v.y * b2f(g.y));
        dst[(size_t)(row + 2) * 1024 + col] = f2b(v.z * b2f(g.z));
        dst[(size_t)(row + 3) * 1024 + col] = f2b(v.w * b2f(g.w));
      } else {  // EPI_OUT: + b_out + residual x, f32 out
        float bias = a0[col];
#pragma unroll
        for (int i = 0; i < 4; ++i)
          fout[(size_t)(row + i) * 512 + col] = v[i] + bias + xres[(size_t)(row + i) * 512 + col];
      }
    }
  }
}

__global__ void conv_b(const float* in, u16* out, int n) {
  int i = (blockIdx.x * blockDim.x + threadIdx.x) * 4;
  if (i >= n) return;
  float4 f = *(const float4*)(in + i);
  *(ushort4*)(out + i) = make_ushort4(f2b(f.x), f2b(f.y), f2b(f.z), f2b(f.w));
}

// out[C][R] = bf16(in[R][C]) — coalesced writes, tiny tensors
__global__ void transpose_b(const float* in, u16* out, int R, int C) {
  int o = blockIdx.x * blockDim.x + threadIdx.x;
  if (o >= R * C) return;
  int c = o / R, r = o - c * R;
  out[o] = f2b(in[(size_t)r * C + c]);
}

extern "C" void kernel_launch(void* const* d_in, const int* in_sizes, int n_in,
                              void* d_out, int out_size, void* d_ws, size_t ws_size,
                              hipStream_t stream) {
  const float* x = (const float*)d_in[0];
  const float* w_hidden = (const float*)d_in[1];
  const float* b_hidden = (const float*)d_in[2];
  const float* w_qk = (const float*)d_in[3];
  const float* q_gamma = (const float*)d_in[4];
  const float* q_beta = (const float*)d_in[5];
  const float* k_gamma = (const float*)d_in[6];
  const float* k_beta = (const float*)d_in[7];
  const float* w_out = (const float*)d_in[8];
  const float* b_out = (const float*)d_in[9];
  float* out = (float*)d_out;

  char* ws = (char*)d_ws;
  size_t off = 0;
  auto alloc = [&](size_t bytes) { char* p = ws + off; off += (bytes + 255) & ~255ull; return p; };
  u16* xb     = (u16*)alloc(16384ull * 512 * 2);
  u16* wh_t   = (u16*)alloc(2048ull * 512 * 2);
  u16* wqk_t  = (u16*)alloc(128ull * 512 * 2);
  u16* wout_t = (u16*)alloc(512ull * 1024 * 2);
  u16* v_t    = (u16*)alloc(1024ull * 16384 * 2);
  u16* g_t    = (u16*)alloc(1024ull * 16384 * 2);
  u16* qb_a   = (u16*)alloc(16384ull * 128 * 2);
  u16* kb_a   = (u16*)alloc(16384ull * 128 * 2);
  u16* attnb  = (u16*)alloc(4ull * 4096 * 4096 * 2);
  u16* out1b  = (u16*)alloc(16384ull * 1024 * 2);

  conv_b<<<(16384 * 512 / 4 + 255) / 256, 256, 0, stream>>>(x, xb, 16384 * 512);
  transpose_b<<<(512 * 2048 + 255) / 256, 256, 0, stream>>>(w_hidden, wh_t, 512, 2048);
  transpose_b<<<(512 * 128 + 255) / 256, 256, 0, stream>>>(w_qk, wqk_t, 512, 128);
  transpose_b<<<(1024 * 512 + 255) / 256, 256, 0, stream>>>(w_out, wout_t, 1024, 512);

  // GEMM1: hid = x @ Wh (+bias) -> v_t, g_t (transposed bf16)
  gemm_tn<EPI_HID><<<dim3(16, 128, 1), 256, 0, stream>>>(
      (const char*)xb, (const char*)wh_t, 0, 0, 1024, 1024, 8,
      v_t, g_t, b_hidden, nullptr, nullptr, nullptr, nullptr, nullptr);
  // GEMM2: qk = x @ Wqk -> q,k (offset-scale)
  gemm_tn<EPI_QK><<<dim3(1, 128, 1), 256, 0, stream>>>(
      (const char*)xb, (const char*)wqk_t, 0, 0, 1024, 1024, 8,
      qb_a, kb_a, q_gamma, q_beta, k_gamma, k_beta, nullptr, nullptr);
  // sim = q @ k^T, relu^2(scale*) -> attn bf16 (per batch)
  gemm_tn<EPI_ATTN><<<dim3(32, 32, 4), 256, 0, stream>>>(
      (const char*)qb_a, (const char*)kb_a, 4096ll * 256, 4096ll * 256, 256, 256, 2,
      attnb, nullptr, nullptr, nullptr, nullptr, nullptr, nullptr, nullptr);
  // out1 = (attn @ v) * gate -> bf16
  gemm_tn<EPI_PV><<<dim3(8, 32, 4), 256, 0, stream>>>(
      (const char*)attnb, (const char*)v_t, 4096ll * 8192, 8192, 8192, 32768, 64,
      out1b, g_t, nullptr, nullptr, nullptr, nullptr, nullptr, nullptr);
  // out = out1 @ Wout + b_out + x
  gemm_tn<EPI_OUT><<<dim3(4, 128, 1), 256, 0, stream>>>(
      (const char*)out1b, (const char*)wout_t, 0, 0, 2048, 2048, 16,
      nullptr, nullptr, b_out, nullptr, nullptr, nullptr, out, x);
}

// Round 3
// 320.650 us; speedup vs baseline: 1.1110x; 1.1110x over previous
//
#include <hip/hip_runtime.h>
#include <hip/hip_bf16.h>

typedef __attribute__((ext_vector_type(8))) short bf16x8;
typedef __attribute__((ext_vector_type(4))) float f32x4;
typedef unsigned short u16;

__device__ __forceinline__ u16 f2b(float f) {
  __hip_bfloat16 h = __float2bfloat16(f);
  return __builtin_bit_cast(unsigned short, h);
}
__device__ __forceinline__ float b2f(u16 u) {
  __hip_bfloat16 h = __builtin_bit_cast(__hip_bfloat16, u);
  return __bfloat162float(h);
}

#define BAR() __builtin_amdgcn_s_barrier()
#define LGKM0() do { asm volatile("s_waitcnt lgkmcnt(0)" ::: "memory"); __builtin_amdgcn_sched_barrier(0); } while (0)
#define VMCNT4() asm volatile("s_waitcnt vmcnt(4)" ::: "memory")
#define VMCNT0() asm volatile("s_waitcnt vmcnt(0)" ::: "memory")

#define EPI_HID 0
#define EPI_QK 1
#define EPI_ATTN 2
#define EPI_PV 3
#define EPI_OUT 4

// ---------- 128^2 2-phase kernel (kept for small-N GEMMs: QK, OUT) ----------
__device__ __forceinline__ void stage_tile(char* sbase, const char* gbase, int ld_bytes, int tid) {
#pragma unroll
  for (int i = 0; i < 4; ++i) {
    int o = (i * 256 + tid) * 16;
    int row = o >> 7;
    int cb = o & 127;
    int scb = cb ^ ((row & 7) << 4);
    const char* src = gbase + (long)row * ld_bytes + scb;
    __builtin_amdgcn_global_load_lds((const __attribute__((address_space(1))) void*)src,
                                     (__attribute__((address_space(3))) void*)(sbase + o),
                                     16, 0, 0);
  }
}

template <int EPI>
__global__ __launch_bounds__(256, 2) void gemm_tn(
    const char* Ab, const char* Bb, long sAbat, long sBbat,
    int lda_b, int ldb_b, int nkt,
    u16* o0, u16* o1,
    const float* a0, const float* a1, const float* a2, const float* a3,
    float* fout, const float* xres) {
  __shared__ __align__(16) char lds[32768];
  char* sA = lds;
  char* sB = lds + 16384;
  const int tid = threadIdx.x;
  const int lane = tid & 63;
  const int wave = tid >> 6;
  const int wm = wave >> 1, wn = wave & 1;
  const int l16 = lane & 15, lq = lane >> 4;
  const int bat = blockIdx.z;
  const int row0 = blockIdx.y * 128;
  const int col0 = blockIdx.x * 128;

  const char* Abase = Ab + (long)bat * sAbat + (long)row0 * lda_b;
  const char* Bbase = Bb + (long)bat * sBbat + (long)col0 * ldb_b;

  f32x4 acc[4][4];
#pragma unroll
  for (int i = 0; i < 4; ++i)
#pragma unroll
    for (int j = 0; j < 4; ++j) acc[i][j] = (f32x4){0.f, 0.f, 0.f, 0.f};

  for (int kt = 0; kt < nkt; ++kt) {
    stage_tile(sA, Abase + (long)kt * 128, lda_b, tid);
    stage_tile(sB, Bbase + (long)kt * 128, ldb_b, tid);
    __syncthreads();
#pragma unroll
    for (int kk = 0; kk < 2; ++kk) {
      bf16x8 af[4], bfr[4];
#pragma unroll
      for (int mf = 0; mf < 4; ++mf) {
        int r = wm * 64 + mf * 16 + l16;
        int kb = kk * 64 + lq * 16;
        af[mf] = *(const bf16x8*)(sA + r * 128 + (kb ^ ((r & 7) << 4)));
      }
#pragma unroll
      for (int nf = 0; nf < 4; ++nf) {
        int r = wn * 64 + nf * 16 + l16;
        int kb = kk * 64 + lq * 16;
        bfr[nf] = *(const bf16x8*)(sB + r * 128 + (kb ^ ((r & 7) << 4)));
      }
#pragma unroll
      for (int mf = 0; mf < 4; ++mf)
#pragma unroll
        for (int nf = 0; nf < 4; ++nf)
          acc[mf][nf] = __builtin_amdgcn_mfma_f32_16x16x32_bf16(af[mf], bfr[nf], acc[mf][nf], 0, 0, 0);
    }
    __syncthreads();
  }

#pragma unroll
  for (int mf = 0; mf < 4; ++mf) {
#pragma unroll
    for (int nf = 0; nf < 4; ++nf) {
      const int row = row0 + wm * 64 + mf * 16 + lq * 4;
      const int col = col0 + wn * 64 + nf * 16 + l16;
      f32x4 v = acc[mf][nf];
      if constexpr (EPI == EPI_QK) {
        float qg = a0[col], qbt = a1[col], kg = a2[col], kbt = a3[col];
#pragma unroll
        for (int i = 0; i < 4; ++i) {
          float t = v[i];
          o0[(size_t)(row + i) * 128 + col] = f2b(t * qg + qbt);
          o1[(size_t)(row + i) * 128 + col] = f2b(t * kg + kbt);
        }
      } else if constexpr (EPI == EPI_OUT) {
        float bias = a0[col];
#pragma unroll
        for (int i = 0; i < 4; ++i)
          fout[(size_t)(row + i) * 512 + col] = v[i] + bias + xres[(size_t)(row + i) * 512 + col];
      }
    }
  }
}

// ---------- 256^2 8-phase kernel (GEMM1, ATTN, PV) ----------
// 512 threads = 8 waves (2m x 4n); BK=64; LDS 128KiB = 2 bufs x (A 32K + B 32K),
// halves of 16KB ([128 rows][128B], XOR-swizzled byte ^= (row&7)<<4).
__device__ __forceinline__ void stage_half(char* sbase, const char* gbase, long ld, int tid) {
#pragma unroll
  for (int i = 0; i < 2; ++i) {
    int o = (i * 512 + tid) * 16;
    int row = o >> 7;
    int cb = o & 127;
    int scb = cb ^ ((row & 7) << 4);
    const char* src = gbase + (long)row * ld + scb;
    __builtin_amdgcn_global_load_lds((const __attribute__((address_space(1))) void*)src,
                                     (__attribute__((address_space(3))) void*)(sbase + o),
                                     16, 0, 0);
  }
}

template <int EPI>
__global__ __launch_bounds__(512, 2) void gemm256(
    const char* Ab, const char* Bb, long sAbat, long sBbat,
    long lda, long ldb, int nkt, int nx,
    u16* o0, u16* o1,
    const float* a0, float* fout, const float* xres) {
  extern __shared__ __align__(16) char lds[];
  const int tid = threadIdx.x;
  const int lane = tid & 63;
  const int wave = tid >> 6;
  const int wm = wave >> 2;        // 0..1 -> rows wm*128
  const int wn = wave & 3;         // 0..3 -> cols wn*64
  const int l16 = lane & 15, lq = lane >> 4;
  const int bat = blockIdx.y;

  // T1 bijective XCD swizzle (gridDim.x % 8 == 0 for all our launches)
  const int nwg = gridDim.x;
  const int qq = nwg >> 3;
  const int fid = blockIdx.x;
  const int swz = (fid & 7) * qq + (fid >> 3);
  const int row0 = (swz / nx) * 256;
  const int col0 = (swz % nx) * 256;

  const char* gA = Ab + (long)bat * sAbat + (long)row0 * lda;
  const char* gB = Bb + (long)bat * sBbat + (long)col0 * ldb;

  f32x4 acc[8][4];
#pragma unroll
  for (int i = 0; i < 8; ++i)
#pragma unroll
    for (int j = 0; j < 4; ++j) acc[i][j] = (f32x4){0.f, 0.f, 0.f, 0.f};

  // per-lane swizzle mask; read row = 16*m + l16 so (row&7) == (l16&7)
  const int kmask = (l16 & 7) << 4;

  // prologue: tile0 fully (B then A), then B-halves of tile1
  stage_half(lds + 32768, gB, ldb, tid);
  stage_half(lds + 32768 + 16384, gB + 128 * ldb, ldb, tid);
  stage_half(lds, gA, lda, tid);
  stage_half(lds + 16384, gA + 128 * lda, lda, tid);
  if (nkt > 1) {
    stage_half(lds + 65536 + 32768, gB + 128, ldb, tid);
    stage_half(lds + 65536 + 32768 + 16384, gB + 128 * ldb + 128, ldb, tid);
    VMCNT4();
  } else {
    VMCNT0();
  }
  BAR();

  bf16x8 af[4][2], bfr[4][2];

  for (int t = 0; t < nkt; ++t) {
    const char* buf = lds + (t & 1) * 65536;
    const char* myA = buf + wm * 16384;
    const char* myB = buf + 32768 + (wn >> 1) * 16384;
    const int rB = (wn & 1) * 64;
    char* stA = lds + ((t + 1) & 1) * 65536;              // A halves of tile t+1
    char* stB = lds + (t & 1) * 65536 + 32768;            // B halves of tile t+2
    const bool sA_ok = (t + 1) < nkt;
    const bool sB_ok = (t + 2) < nkt;

    // ---- P1: read B nq0 (4) + A mq0 (8); stage hA0(t+1)
#pragma unroll
    for (int nf = 0; nf < 2; ++nf) {
      int r = rB + nf * 16 + l16;
#pragma unroll
      for (int kh = 0; kh < 2; ++kh)
        bfr[nf][kh] = *(const bf16x8*)(myB + r * 128 + ((kh * 64 + lq * 16) ^ kmask));
    }
#pragma unroll
    for (int mf = 0; mf < 4; ++mf) {
      int r = mf * 16 + l16;
#pragma unroll
      for (int kh = 0; kh < 2; ++kh)
        af[mf][kh] = *(const bf16x8*)(myA + r * 128 + ((kh * 64 + lq * 16) ^ kmask));
    }
    if (sA_ok) stage_half(stA, gA + (long)(t + 1) * 128, lda, tid);
    BAR();
    LGKM0();
    __builtin_amdgcn_s_setprio(1);
#pragma unroll
    for (int mf = 0; mf < 4; ++mf)
#pragma unroll
      for (int nf = 0; nf < 2; ++nf)
#pragma unroll
        for (int kh = 0; kh < 2; ++kh)
          acc[mf][nf] = __builtin_amdgcn_mfma_f32_16x16x32_bf16(af[mf][kh], bfr[nf][kh], acc[mf][nf], 0, 0, 0);
    __builtin_amdgcn_s_setprio(0);
    BAR();

    // ---- P2: read B nq1 (4); stage hA1(t+1)
#pragma unroll
    for (int nf = 2; nf < 4; ++nf) {
      int r = rB + nf * 16 + l16;
#pragma unroll
      for (int kh = 0; kh < 2; ++kh)
        bfr[nf][kh] = *(const bf16x8*)(myB + r * 128 + ((kh * 64 + lq * 16) ^ kmask));
    }
    if (sA_ok) stage_half(stA + 16384, gA + 128 * lda + (long)(t + 1) * 128, lda, tid);
    BAR();
    LGKM0();
    __builtin_amdgcn_s_setprio(1);
#pragma unroll
    for (int mf = 0; mf < 4; ++mf)
#pragma unroll
      for (int nf = 2; nf < 4; ++nf)
#pragma unroll
        for (int kh = 0; kh < 2; ++kh)
          acc[mf][nf] = __builtin_amdgcn_mfma_f32_16x16x32_bf16(af[mf][kh], bfr[nf][kh], acc[mf][nf], 0, 0, 0);
    __builtin_amdgcn_s_setprio(0);
    BAR();

    // ---- P3: read A mq1 (8); stage hB0(t+2)
#pragma unroll
    for (int mf = 0; mf < 4; ++mf) {
      int r = 64 + mf * 16 + l16;
#pragma unroll
      for (int kh = 0; kh < 2; ++kh)
        af[mf][kh] = *(const bf16x8*)(myA + r * 128 + ((kh * 64 + lq * 16) ^ kmask));
    }
    if (sB_ok) stage_half(stB, gB + (long)(t + 2) * 128, ldb, tid);
    BAR();
    LGKM0();
    __builtin_amdgcn_s_setprio(1);
#pragma unroll
    for (int mf = 0; mf < 4; ++mf)
#pragma unroll
      for (int nf = 2; nf < 4; ++nf)
#pragma unroll
        for (int kh = 0; kh < 2; ++kh)
          acc[4 + mf][nf] = __builtin_amdgcn_mfma_f32_16x16x32_bf16(af[mf][kh], bfr[nf][kh], acc[4 + mf][nf], 0, 0, 0);
    __builtin_amdgcn_s_setprio(0);
    BAR();

    // ---- P4: no reads; stage hB1(t+2); compute (mq1, nq0)
    if (sB_ok) stage_half(stB + 16384, gB + 128 * ldb + (long)(t + 2) * 128, ldb, tid);
    __builtin_amdgcn_s_setprio(1);
#pragma unroll
    for (int mf = 0; mf < 4; ++mf)
#pragma unroll
      for (int nf = 0; nf < 2; ++nf)
#pragma unroll
        for (int kh = 0; kh < 2; ++kh)
          acc[4 + mf][nf] = __builtin_amdgcn_mfma_f32_16x16x32_bf16(af[mf][kh], bfr[nf][kh], acc[4 + mf][nf], 0, 0, 0);
    __builtin_amdgcn_s_setprio(0);
    if (sB_ok) { VMCNT4(); } else if (sA_ok) { VMCNT0(); }
    BAR();
  }

  // epilogue
#pragma unroll
  for (int mi = 0; mi < 8; ++mi) {
#pragma unroll
    for (int ni = 0; ni < 4; ++ni) {
      const int row = row0 + wm * 128 + mi * 16 + lq * 4;
      const int col = col0 + wn * 64 + ni * 16 + l16;
      f32x4 v = acc[mi][ni];
      if constexpr (EPI == EPI_HID) {
        float bias = a0[col];
        u16* dst = (col < 1024) ? (o0 + (size_t)col * 16384 + row)
                                : (o1 + (size_t)(col - 1024) * 16384 + row);
        *(ushort4*)dst = make_ushort4(f2b(v.x + bias), f2b(v.y + bias), f2b(v.z + bias), f2b(v.w + bias));
      } else if constexpr (EPI == EPI_ATTN) {
        const float scale = 0.088388347648318447f;  // 128^-0.5
        u16* dst = o0 + (size_t)bat * 4096 * 4096;
#pragma unroll
        for (int i = 0; i < 4; ++i) {
          float t = v[i] * scale;
          t = t > 0.f ? t * t : 0.f;
          dst[(size_t)(row + i) * 4096 + col] = f2b(t);
        }
      } else if constexpr (EPI == EPI_PV) {
        const u16* gt = o1 + (size_t)col * 16384 + (size_t)bat * 4096 + row;
        ushort4 g = *(const ushort4*)gt;
        u16* dst = o0 + (size_t)bat * 4096 * 1024;
        dst[(size_t)(row + 0) * 1024 + col] = f2b(v.x * b2f(g.x));
        dst[(size_t)(row + 1) * 1024 + col] = f2b(v.y * b2f(g.y));
        dst[(size_t)(row + 2) * 1024 + col] = f2b(v.z * b2f(g.z));
        dst[(size_t)(row + 3) * 1024 + col] = f2b(v.w * b2f(g.w));
      }
    }
  }
}

__global__ void conv_b(const float* in, u16* out, int n) {
  int i = (blockIdx.x * blockDim.x + threadIdx.x) * 4;
  if (i >= n) return;
  float4 f = *(const float4*)(in + i);
  *(ushort4*)(out + i) = make_ushort4(f2b(f.x), f2b(f.y), f2b(f.z), f2b(f.w));
}

__global__ void transpose_b(const float* in, u16* out, int R, int C) {
  int o = blockIdx.x * blockDim.x + threadIdx.x;
  if (o >= R * C) return;
  int c = o / R, r = o - c * R;
  out[o] = f2b(in[(size_t)r * C + c]);
}

extern "C" void kernel_launch(void* const* d_in, const int* in_sizes, int n_in,
                              void* d_out, int out_size, void* d_ws, size_t ws_size,
                              hipStream_t stream) {
  const float* x = (const float*)d_in[0];
  const float* w_hidden = (const float*)d_in[1];
  const float* b_hidden = (const float*)d_in[2];
  const float* w_qk = (const float*)d_in[3];
  const float* q_gamma = (const float*)d_in[4];
  const float* q_beta = (const float*)d_in[5];
  const float* k_gamma = (const float*)d_in[6];
  const float* k_beta = (const float*)d_in[7];
  const float* w_out = (const float*)d_in[8];
  const float* b_out = (const float*)d_in[9];
  float* out = (float*)d_out;

  char* ws = (char*)d_ws;
  size_t off = 0;
  auto alloc = [&](size_t bytes) { char* p = ws + off; off += (bytes + 255) & ~255ull; return p; };
  u16* xb     = (u16*)alloc(16384ull * 512 * 2);
  u16* wh_t   = (u16*)alloc(2048ull * 512 * 2);
  u16* wqk_t  = (u16*)alloc(128ull * 512 * 2);
  u16* wout_t = (u16*)alloc(512ull * 1024 * 2);
  u16* v_t    = (u16*)alloc(1024ull * 16384 * 2);
  u16* g_t    = (u16*)alloc(1024ull * 16384 * 2);
  u16* qb_a   = (u16*)alloc(16384ull * 128 * 2);
  u16* kb_a   = (u16*)alloc(16384ull * 128 * 2);
  u16* attnb  = (u16*)alloc(4ull * 4096 * 4096 * 2);
  u16* out1b  = (u16*)alloc(16384ull * 1024 * 2);

  (void)hipFuncSetAttribute((const void*)gemm256<EPI_HID>, hipFuncAttributeMaxDynamicSharedMemorySize, 131072);
  (void)hipFuncSetAttribute((const void*)gemm256<EPI_ATTN>, hipFuncAttributeMaxDynamicSharedMemorySize, 131072);
  (void)hipFuncSetAttribute((const void*)gemm256<EPI_PV>, hipFuncAttributeMaxDynamicSharedMemorySize, 131072);

  conv_b<<<(16384 * 512 / 4 + 255) / 256, 256, 0, stream>>>(x, xb, 16384 * 512);
  transpose_b<<<(512 * 2048 + 255) / 256, 256, 0, stream>>>(w_hidden, wh_t, 512, 2048);
  transpose_b<<<(512 * 128 + 255) / 256, 256, 0, stream>>>(w_qk, wqk_t, 512, 128);
  transpose_b<<<(1024 * 512 + 255) / 256, 256, 0, stream>>>(w_out, wout_t, 1024, 512);

  // GEMM1: hid = x @ Wh (+bias) -> v_t, g_t (transposed bf16). M=16384 N=2048 K=512
  gemm256<EPI_HID><<<dim3(512, 1), 512, 131072, stream>>>(
      (const char*)xb, (const char*)wh_t, 0, 0, 1024, 1024, 8, 8,
      v_t, g_t, b_hidden, nullptr, nullptr);
  // GEMM2: qk = x @ Wqk -> q,k (offset-scale). N=128 -> old kernel
  gemm_tn<EPI_QK><<<dim3(1, 128, 1), 256, 0, stream>>>(
      (const char*)xb, (const char*)wqk_t, 0, 0, 1024, 1024, 8,
      qb_a, kb_a, q_gamma, q_beta, k_gamma, k_beta, nullptr, nullptr);
  // sim = q @ k^T, relu^2(scale*) -> attn bf16. per batch 4096x4096, K=128
  gemm256<EPI_ATTN><<<dim3(256, 4), 512, 131072, stream>>>(
      (const char*)qb_a, (const char*)kb_a, 4096ll * 256, 4096ll * 256, 256, 256, 2, 16,
      attnb, nullptr, nullptr, nullptr, nullptr);
  // out1 = (attn @ v) * gate. per batch M=4096 N=1024 K=4096
  gemm256<EPI_PV><<<dim3(64, 4), 512, 131072, stream>>>(
      (const char*)attnb, (const char*)v_t, 4096ll * 8192, 8192, 8192, 32768, 64, 4,
      out1b, g_t, nullptr, nullptr, nullptr);
  // out = out1 @ Wout + b_out + x. M=16384 N=512 K=1024 -> old kernel
  gemm_tn<EPI_OUT><<<dim3(4, 128, 1), 256, 0, stream>>>(
      (const char*)out1b, (const char*)wout_t, 0, 0, 2048, 2048, 16,
      nullptr, nullptr, b_out, nullptr, nullptr, nullptr, out, x);
}